// Round 5
// baseline (486.393 us; speedup 1.0000x reference)
//
#include <hip/hip_runtime.h>

typedef short s16x8 __attribute__((ext_vector_type(8)));
typedef float f32x4 __attribute__((ext_vector_type(4)));

#define HN 8
#define PP 4
#define DH 32
#define NQc 8192
#define NVc 16384
#define EE 256
#define HWc 128

__device__ __forceinline__ unsigned short f2bf(float x) {
  unsigned u = __float_as_uint(x);
  u += 0x7FFF + ((u >> 16) & 1);  // RNE
  return (unsigned short)(u >> 16);
}
__device__ __forceinline__ float bf2f(unsigned short h) {
  return __uint_as_float(((unsigned)h) << 16);
}
// packed f32x2 -> bf16x2, RNE (same rounding as f2bf)
__device__ __forceinline__ unsigned cvt2(float lo, float hi) {
  unsigned r;
  asm("v_cvt_pk_bf16_f32 %0, %1, %2" : "=v"(r) : "v"(lo), "v"(hi));
  return r;
}

// ---------- weight prep: transpose+convert to bf16 [N][K], build bcat ----------
__global__ __launch_bounds__(256) void wprep(
    const float* __restrict__ Wval, const float* __restrict__ Wout,
    const float* __restrict__ Woff, const float* __restrict__ Wattn,
    const float* __restrict__ boff, const float* __restrict__ battn,
    unsigned short* __restrict__ wvt, unsigned short* __restrict__ wot,
    unsigned short* __restrict__ wct, float* __restrict__ bcat) {
  int g = blockIdx.x * 256 + threadIdx.x;
  if (g < 65536) {
    int n = g >> 8, k = g & 255;
    wvt[n * 256 + k] = f2bf(Wval[k * 256 + n]);
  } else if (g < 131072) {
    int g2 = g - 65536;
    int n = g2 >> 8, k = g2 & 255;
    wot[n * 256 + k] = f2bf(Wout[k * 256 + n]);
  } else if (g < 163840) {
    int g2 = g - 131072;
    int n = g2 >> 8, k = g2 & 255;
    float v = 0.f;
    if (n < 64) v = Woff[k * 64 + n];
    else if (n < 96) v = Wattn[k * 32 + (n - 64)];
    wct[n * 256 + k] = f2bf(v);
  } else if (g < 163968) {
    int c = g - 163840;
    bcat[c] = (c < 64) ? boff[c] : ((c < 96) ? battn[c - 64] : 0.f);
  }
}

// ---------- bf16 MFMA GEMM, BM=BN=128, BK=32, 4 waves x (4x4) 16x16x32 tiles ----
// v6: NO LDS in the K-loop, NO barriers. MFMA fragments loaded directly from
// global: W (128 KB) is L2-resident; A read as full 128B-line chunks per row.
// f32->bf16 at the use point (cvt_pk, RNE). Waves stream independently; the
// fully-unrolled K-loop lets the compiler pipeline loads across iterations
// (the per-K-step __syncthreads/vmcnt(0) drain was the round-2..4 ceiling).
// Swapped MFMA operands (acc = C^T: row=channel, col=spatial).
// Grid: (N-blocks, M-blocks) so A-panel-sharing blocks are dispatch-adjacent.
#define MODE_VAL 0
#define MODE_PLAIN 1
#define MODE_OUT 2

template <int MODE>
struct SmemBytes { static constexpr int v = 16; };              // VAL: unused
template <> struct SmemBytes<MODE_PLAIN> { static constexpr int v = 51200; };  // epi 128x100 f32
template <> struct SmemBytes<MODE_OUT>   { static constexpr int v = 33792; };  // epi 64x132 f32

template <int MODE, bool ABF16>
__global__ __launch_bounds__(256) void mfma_gemm(
    const void* __restrict__ Ain, const unsigned short* __restrict__ Wt,
    const float* __restrict__ bias, const float* __restrict__ resid,
    const float* __restrict__ ref2d, unsigned int* __restrict__ meta,
    void* __restrict__ outp) {
  __shared__ __align__(16) char smem[SmemBytes<MODE>::v];
  const int t = threadIdx.x;
  const int lane = t & 63, wave = t >> 6;
  const int lane15 = lane & 15, quad = lane >> 4;
  const int wr = wave >> 1, wc = wave & 1;
  const int bn = blockIdx.x * 128, bm = blockIdx.y * 128;

  f32x4 acc[4][4];
#pragma unroll
  for (int i = 0; i < 4; ++i)
#pragma unroll
    for (int j = 0; j < 4; ++j)
#pragma unroll
      for (int r = 0; r < 4; ++r) acc[i][j][r] = 0.f;

  // per-wave fragment row bases (M side and N side)
  const int arow = bm + wr * 64 + lane15;  // + tm*16
  const int wrow = bn + wc * 64 + lane15;  // + tn*16
  const float* Af = (const float*)Ain;
  const unsigned short* Ab = (const unsigned short*)Ain;

#pragma unroll
  for (int kk = 0; kk < 8; ++kk) {
    const int k0 = kk * 32;
    s16x8 af[4], bfr[4];
#pragma unroll
    for (int tm = 0; tm < 4; ++tm) {
      if (!ABF16) {
        const float* p = Af + (size_t)(arow + tm * 16) * 256 + k0 + quad * 8;
        const float4 x0 = *(const float4*)p;
        const float4 x1 = *(const float4*)(p + 4);
        union { unsigned u[4]; s16x8 v; } tu;
        tu.u[0] = cvt2(x0.x, x0.y); tu.u[1] = cvt2(x0.z, x0.w);
        tu.u[2] = cvt2(x1.x, x1.y); tu.u[3] = cvt2(x1.z, x1.w);
        af[tm] = tu.v;
      } else {
        af[tm] = *(const s16x8*)(Ab + (size_t)(arow + tm * 16) * 256 + k0 + quad * 8);
      }
    }
#pragma unroll
    for (int tn = 0; tn < 4; ++tn)
      bfr[tn] = *(const s16x8*)(Wt + (size_t)(wrow + tn * 16) * 256 + k0 + quad * 8);
#pragma unroll
    for (int tm = 0; tm < 4; ++tm)
#pragma unroll
      for (int tn = 0; tn < 4; ++tn)
        acc[tm][tn] = __builtin_amdgcn_mfma_f32_16x16x32_bf16(bfr[tn], af[tm], acc[tm][tn], 0, 0, 0);
  }

  if (MODE == MODE_VAL) {
    // ---- direct ushort4 stores to (B,HN,NV,DH); 4 consecutive dh per thread ----
    unsigned short* outs = (unsigned short*)outp;
    const size_t b = (size_t)(bm >> 14);
    const int n0 = bm & (NVc - 1);
#pragma unroll
    for (int tn = 0; tn < 4; ++tn) {
      const int ch0 = bn + wc * 64 + tn * 16 + quad * 4;  // global channel
      const float4 b4 = *(const float4*)&bias[ch0];
      const int h = ch0 >> 5, dh0 = ch0 & 31;
#pragma unroll
      for (int tm = 0; tm < 4; ++tm) {
        const int n = n0 + wr * 64 + tm * 16 + lane15;
        ushort4 o;
        o.x = f2bf(acc[tm][tn][0] + b4.x);
        o.y = f2bf(acc[tm][tn][1] + b4.y);
        o.z = f2bf(acc[tm][tn][2] + b4.z);
        o.w = f2bf(acc[tm][tn][3] + b4.w);
        *(ushort4*)(outs + ((b * HN + h) * NVc + n) * DH + dh0) = o;
      }
    }
  } else if (MODE == MODE_PLAIN) {
    // ---- float4 LDS writes (stride 100), then fused softmax/loc prep ----
    float* Cf = (float*)smem;  // 128 x 100
#pragma unroll
    for (int tn = 0; tn < 4; ++tn) {
      const int col0 = wc * 64 + tn * 16 + quad * 4;
      if (col0 < 96) {
        const float4 b4 = *(const float4*)&bias[col0];
#pragma unroll
        for (int tm = 0; tm < 4; ++tm) {
          const int m = wr * 64 + tm * 16 + lane15;
          float4 v;
          v.x = acc[tm][tn][0] + b4.x;
          v.y = acc[tm][tn][1] + b4.y;
          v.z = acc[tm][tn][2] + b4.z;
          v.w = acc[tm][tn][3] + b4.w;
          *(float4*)&Cf[m * 100 + col0] = v;
        }
      }
    }
    __syncthreads();
#pragma unroll
    for (int i = 0; i < 4; ++i) {
      const int task = i * 256 + t;
      const int h = task & 7, rowl = task >> 3;
      const int bq = bm + rowl;
      const float* row = Cf + rowl * 100;
      const float rx = ref2d[(size_t)bq * 2 + 0];
      const float ry = ref2d[(size_t)bq * 2 + 1];
      const float l0 = row[64 + h * 4 + 0], l1 = row[64 + h * 4 + 1];
      const float l2 = row[64 + h * 4 + 2], l3 = row[64 + h * 4 + 3];
      const float mx = fmaxf(fmaxf(l0, l1), fmaxf(l2, l3));
      float e0 = __expf(l0 - mx), e1 = __expf(l1 - mx), e2 = __expf(l2 - mx), e3 = __expf(l3 - mx);
      const float inv = 1.0f / (e0 + e1 + e2 + e3);
      float ee[4] = {e0, e1, e2, e3};
      unsigned int* m = meta + ((size_t)bq * 8 + h) * 20;
      uint4 pk;
      float4 wts[4];
#pragma unroll
      for (int p = 0; p < PP; ++p) {
        const float a = ee[p] * inv;
        const float ox = row[h * 8 + p * 2 + 0];
        const float oy = row[h * 8 + p * 2 + 1];
        const float x = (rx + ox * (1.0f / HWc)) * (float)HWc - 0.5f;
        const float y = (ry + oy * (1.0f / HWc)) * (float)HWc - 0.5f;
        const float x0f = floorf(x), y0f = floorf(y);
        const int x0 = (int)x0f, y0 = (int)y0f;
        const float wx1 = x - x0f, wx0 = 1.f - wx1;
        const float wy1 = y - y0f, wy0 = 1.f - wy1;
        const bool vx0 = (unsigned)x0 < (unsigned)HWc, vx1 = (unsigned)(x0 + 1) < (unsigned)HWc;
        const bool vy0 = (unsigned)y0 < (unsigned)HWc, vy1 = (unsigned)(y0 + 1) < (unsigned)HWc;
        const int xi0 = min(max(x0, 0), HWc - 1), xi1 = min(max(x0 + 1, 0), HWc - 1);
        const int yi0 = min(max(y0, 0), HWc - 1), yi1 = min(max(y0 + 1, 0), HWc - 1);
        const unsigned pv = (unsigned)xi0 | ((unsigned)yi0 << 8) | ((unsigned)xi1 << 16) | ((unsigned)yi1 << 24);
        if (p == 0) pk.x = pv; else if (p == 1) pk.y = pv; else if (p == 2) pk.z = pv; else pk.w = pv;
        float4 w;
        w.x = (vx0 && vy0) ? a * wx0 * wy0 : 0.f;
        w.y = (vx1 && vy0) ? a * wx1 * wy0 : 0.f;
        w.z = (vx0 && vy1) ? a * wx0 * wy1 : 0.f;
        w.w = (vx1 && vy1) ? a * wx1 * wy1 : 0.f;
        wts[p] = w;
      }
      *(uint4*)m = pk;
#pragma unroll
      for (int p = 0; p < PP; ++p) *(float4*)&m[4 + p * 4] = wts[p];
    }
  } else {
    // ---- MODE_OUT: 2-pass LDS transpose (float4 writes), coalesced resid/store ----
    float* Cf = (float*)smem;  // 64 x 132
    float* outf = (float*)outp;
#pragma unroll
    for (int pass = 0; pass < 2; ++pass) {
      __syncthreads();
      if (wr == pass) {
#pragma unroll
        for (int tn = 0; tn < 4; ++tn) {
          const int col0 = wc * 64 + tn * 16 + quad * 4;   // channel within tile
          const float4 b4 = *(const float4*)&bias[bn + col0];
#pragma unroll
          for (int tm = 0; tm < 4; ++tm) {
            const int rowl = tm * 16 + lane15;             // spatial within half-tile
            float4 v;
            v.x = acc[tm][tn][0] + b4.x;
            v.y = acc[tm][tn][1] + b4.y;
            v.z = acc[tm][tn][2] + b4.z;
            v.w = acc[tm][tn][3] + b4.w;
            *(float4*)&Cf[rowl * 132 + col0] = v;
          }
        }
      }
      __syncthreads();
#pragma unroll
      for (int i = 0; i < 8; ++i) {
        const int id = i * 256 + t;
        const int n = id >> 5, c = id & 31;
        const size_t row = (size_t)bm + pass * 64 + n;
        float4 v = *(const float4*)&Cf[n * 132 + c * 4];
        float4 rs = *(const float4*)(resid + row * 256 + bn + c * 4);
        v.x += rs.x; v.y += rs.y; v.z += rs.z; v.w += rs.w;
        *(float4*)(outf + row * 256 + bn + c * 4) = v;
      }
    }
  }
}

// ---------- gather (bf16 vbuf) + weighted accumulate; bf16 output ----------
__global__ __launch_bounds__(256) void sample_kernel(
    const unsigned short* __restrict__ vbuf,  // (B,HN,NV,DH) bf16
    const unsigned int* __restrict__ meta,
    unsigned short* __restrict__ outs) {      // (B*NQ, 256) bf16
  const int t = threadIdx.x;
  const int d4 = (t & 7) << 2;   // channel group base: 0,4,...,28
  const int ql = t >> 3;         // 32 queries per block
  const int sl = blockIdx.x >> 8;   // b*8+h
  const int qc = blockIdx.x & 255;
  const int b = sl >> 3;
  const int h = sl & 7;
  const int q = qc * 32 + ql;
  const size_t bq = (size_t)b * NQc + q;
  const unsigned int* m = meta + ((size_t)bq * 8 + h) * 20;
  const uint4 pk = *(const uint4*)m;
  const unsigned short* vb = vbuf + (size_t)sl * (NVc * DH) + d4;

  float4 acc = {0.f, 0.f, 0.f, 0.f};
#pragma unroll
  for (int p = 0; p < PP; ++p) {
    const unsigned P = (p == 0) ? pk.x : (p == 1) ? pk.y : (p == 2) ? pk.z : pk.w;
    const float4 w = *(const float4*)(m + 4 + p * 4);
    const int x0 = P & 255, y0 = (P >> 8) & 255, x1 = (P >> 16) & 255, y1 = P >> 24;
    const int r0 = y0 << 12, r1 = y1 << 12;
    const ushort4 v00 = *(const ushort4*)(vb + r0 + (x0 << 5));
    const ushort4 v10 = *(const ushort4*)(vb + r0 + (x1 << 5));
    const ushort4 v01 = *(const ushort4*)(vb + r1 + (x0 << 5));
    const ushort4 v11 = *(const ushort4*)(vb + r1 + (x1 << 5));
    acc.x += w.x * bf2f(v00.x); acc.y += w.x * bf2f(v00.y);
    acc.z += w.x * bf2f(v00.z); acc.w += w.x * bf2f(v00.w);
    acc.x += w.y * bf2f(v10.x); acc.y += w.y * bf2f(v10.y);
    acc.z += w.y * bf2f(v10.z); acc.w += w.y * bf2f(v10.w);
    acc.x += w.z * bf2f(v01.x); acc.y += w.z * bf2f(v01.y);
    acc.z += w.z * bf2f(v01.z); acc.w += w.z * bf2f(v01.w);
    acc.x += w.w * bf2f(v11.x); acc.y += w.w * bf2f(v11.y);
    acc.z += w.w * bf2f(v11.z); acc.w += w.w * bf2f(v11.w);
  }
  ushort4 o;
  o.x = f2bf(acc.x); o.y = f2bf(acc.y); o.z = f2bf(acc.z); o.w = f2bf(acc.w);
  *(ushort4*)(outs + bq * EE + h * DH + d4) = o;
}

extern "C" void kernel_launch(void* const* d_in, const int* in_sizes, int n_in,
                              void* d_out, int out_size, void* d_ws, size_t ws_size,
                              hipStream_t stream) {
  const float* query = (const float*)d_in[0];
  const float* value = (const float*)d_in[1];
  const float* ref2d = (const float*)d_in[2];
  const float* Woff  = (const float*)d_in[4];
  const float* boff  = (const float*)d_in[5];
  const float* Wattn = (const float*)d_in[6];
  const float* battn = (const float*)d_in[7];
  const float* Wval  = (const float*)d_in[8];
  const float* bval  = (const float*)d_in[9];
  const float* Wout  = (const float*)d_in[10];
  const float* bout  = (const float*)d_in[11];
  float* out = (float*)d_out;

  unsigned short* vbuf = (unsigned short*)d_ws;                 // 33,554,432 us (64 MB)
  unsigned int* meta   = (unsigned int*)(vbuf + 33554432);      // 10,485,760 u (40 MB)
  unsigned short* sbuf = (unsigned short*)(meta + 10485760);    // 16,777,216 us (32 MB)
  unsigned short* wvt  = sbuf + 16777216;                       // 65536
  unsigned short* wot  = wvt + 65536;                           // 65536
  unsigned short* wct  = wot + 65536;                           // 32768
  float* bcat          = (float*)(wct + 32768);                 // 128

  wprep<<<641, 256, 0, stream>>>(Wval, Wout, Woff, Wattn, boff, battn, wvt, wot, wct, bcat);

  // grid = (N-blocks, M-blocks): blocks sharing an A panel are dispatch-adjacent
  mfma_gemm<MODE_VAL, false><<<dim3(2, 1024), 256, 0, stream>>>(
      (const void*)value, wvt, bval, nullptr, nullptr, nullptr, (void*)vbuf);

  mfma_gemm<MODE_PLAIN, false><<<dim3(1, 512), 256, 0, stream>>>(
      (const void*)query, wct, bcat, nullptr, ref2d, meta, nullptr);

  sample_kernel<<<16384, 256, 0, stream>>>(vbuf, meta, sbuf);

  mfma_gemm<MODE_OUT, true><<<dim3(2, 512), 256, 0, stream>>>(
      (const void*)sbuf, wot, bout, query, nullptr, nullptr, (void*)out);
}

// Round 9
// 418.423 us; speedup vs baseline: 1.1624x; 1.1624x over previous
//
#include <hip/hip_runtime.h>

typedef short s16x8 __attribute__((ext_vector_type(8)));
typedef float f32x4 __attribute__((ext_vector_type(4)));

#define HN 8
#define PP 4
#define DH 32
#define NQc 8192
#define NVc 16384
#define EE 256
#define HWc 128

__device__ __forceinline__ unsigned short f2bf(float x) {
  unsigned u = __float_as_uint(x);
  u += 0x7FFF + ((u >> 16) & 1);  // RNE
  return (unsigned short)(u >> 16);
}
__device__ __forceinline__ float bf2f(unsigned short h) {
  return __uint_as_float(((unsigned)h) << 16);
}

// ---------- weight prep: transpose+convert to bf16 [N][K], build bcat ----------
__global__ __launch_bounds__(256) void wprep(
    const float* __restrict__ Wval, const float* __restrict__ Wout,
    const float* __restrict__ Woff, const float* __restrict__ Wattn,
    const float* __restrict__ boff, const float* __restrict__ battn,
    unsigned short* __restrict__ wvt, unsigned short* __restrict__ wot,
    unsigned short* __restrict__ wct, float* __restrict__ bcat) {
  int g = blockIdx.x * 256 + threadIdx.x;
  if (g < 65536) {
    int n = g >> 8, k = g & 255;
    wvt[n * 256 + k] = f2bf(Wval[k * 256 + n]);
  } else if (g < 131072) {
    int g2 = g - 65536;
    int n = g2 >> 8, k = g2 & 255;
    wot[n * 256 + k] = f2bf(Wout[k * 256 + n]);
  } else if (g < 163840) {
    int g2 = g - 131072;
    int n = g2 >> 8, k = g2 & 255;
    float v = 0.f;
    if (n < 64) v = Woff[k * 64 + n];
    else if (n < 96) v = Wattn[k * 32 + (n - 64)];
    wct[n * 256 + k] = f2bf(v);
  } else if (g < 163968) {
    int c = g - 163840;
    bcat[c] = (c < 64) ? boff[c] : ((c < 96) ? battn[c - 64] : 0.f);
  }
}

// ---------- bf16 MFMA GEMM, BM=BN=128, BK=32, 4 waves x (4x4) 16x16x32 tiles ----
// v9 (resubmit after r8 infra failure) = best verified pieces: r2's K-loop
// (reg-staged, single LDS buffer, 2 barriers/K-step, reg prefetch after 2nd
// barrier; VAL=84.6us verified) + r3's MODE_OUT LDS-transpose epilogue
// (verified; r2's direct-store OUT was a coalescing regression). Swapped MFMA
// operands (acc = C^T: row=channel, col=spatial). Counted-vmcnt/no-drain
// barrier lane abandoned after two race failures (r6, r7) - m152 lesson.
#define MODE_VAL 0    // epilogue: bf16 direct store -> (B,HN,NV,DH)
#define MODE_PLAIN 1  // epilogue: fused softmax/loc prep -> meta
#define MODE_OUT 2    // epilogue: 2-pass LDS transpose, +bias+resid, f32 store

template <int MODE>
struct SmemBytes { static constexpr int v = 20480; };           // staging only
template <> struct SmemBytes<MODE_PLAIN> { static constexpr int v = 51200; };  // 128x100 f32
template <> struct SmemBytes<MODE_OUT>   { static constexpr int v = 33792; };  // 64x132 f32

template <int MODE, bool ABF16>
__global__ __launch_bounds__(256) void mfma_gemm(
    const void* __restrict__ Ain, const unsigned short* __restrict__ Wt,
    const float* __restrict__ bias, const float* __restrict__ resid,
    const float* __restrict__ ref2d, unsigned int* __restrict__ meta,
    void* __restrict__ outp) {
  __shared__ __align__(16) char smem[SmemBytes<MODE>::v];
  unsigned short* As = (unsigned short*)smem;            // 128 x 40 shorts
  unsigned short* Ws = As + 128 * 40;                    // 128 x 40 shorts
  const int t = threadIdx.x;
  const int lane = t & 63, wave = t >> 6;
  const int lane15 = lane & 15, quad = lane >> 4;
  const int wr = wave >> 1, wc = wave & 1;
  const int bm = blockIdx.x * 128, bn = blockIdx.y * 128;

  f32x4 acc[4][4];
#pragma unroll
  for (int i = 0; i < 4; ++i)
#pragma unroll
    for (int j = 0; j < 4; ++j)
#pragma unroll
      for (int r = 0; r < 4; ++r) acc[i][j][r] = 0.f;

  const int ar = t >> 3, ac = (t & 7) * 4;   // f32 A staging
  const int wr2 = t >> 1, wcp = (t & 1) * 2; // bf16 chunk-pair staging

  float4 av[4];
  uint4 ab0, ab1, wv0, wv1;

#define LOAD_TILE(K0)                                                          \
  do {                                                                         \
    if (!ABF16) {                                                              \
      const float* Af = (const float*)Ain;                                     \
      _Pragma("unroll") for (int i = 0; i < 4; ++i)                            \
          av[i] = *(const float4*)(Af + (size_t)(bm + ar + i * 32) * 256 +     \
                                   (K0) + ac);                                 \
    } else {                                                                   \
      const unsigned short* Ab = (const unsigned short*)Ain;                   \
      ab0 = *(const uint4*)(Ab + (size_t)(bm + wr2) * 256 + (K0) + wcp * 8);   \
      ab1 = *(const uint4*)(Ab + (size_t)(bm + wr2) * 256 + (K0) + wcp * 8 + 8); \
    }                                                                          \
    wv0 = *(const uint4*)(Wt + (size_t)(bn + wr2) * 256 + (K0) + wcp * 8);     \
    wv1 = *(const uint4*)(Wt + (size_t)(bn + wr2) * 256 + (K0) + wcp * 8 + 8); \
  } while (0)

  LOAD_TILE(0);  // prologue

  for (int k0 = 0; k0 < 256; k0 += 32) {
    __syncthreads();  // previous tile's readers done
    if (!ABF16) {
#pragma unroll
      for (int i = 0; i < 4; ++i) {
        ushort4 c;
        c.x = f2bf(av[i].x); c.y = f2bf(av[i].y); c.z = f2bf(av[i].z); c.w = f2bf(av[i].w);
        *(ushort4*)&As[(ar + i * 32) * 40 + ac] = c;
      }
    } else {
      *(uint4*)&As[wr2 * 40 + wcp * 8] = ab0;
      *(uint4*)&As[wr2 * 40 + wcp * 8 + 8] = ab1;
    }
    *(uint4*)&Ws[wr2 * 40 + wcp * 8] = wv0;
    *(uint4*)&Ws[wr2 * 40 + wcp * 8 + 8] = wv1;
    __syncthreads();
    if (k0 < 224) LOAD_TILE(k0 + 32);  // prefetch next tile; in flight under MFMA
    s16x8 af[4], bfr[4];
#pragma unroll
    for (int tm = 0; tm < 4; ++tm)
      af[tm] = *(const s16x8*)&As[(wr * 64 + tm * 16 + lane15) * 40 + quad * 8];
#pragma unroll
    for (int tn = 0; tn < 4; ++tn)
      bfr[tn] = *(const s16x8*)&Ws[(wc * 64 + tn * 16 + lane15) * 40 + quad * 8];
    // swapped operands: acc[tm][tn] = C^T tile; row = channel (quad*4+r), col = spatial (lane15)
#pragma unroll
    for (int tm = 0; tm < 4; ++tm)
#pragma unroll
      for (int tn = 0; tn < 4; ++tn)
        acc[tm][tn] = __builtin_amdgcn_mfma_f32_16x16x32_bf16(bfr[tn], af[tm], acc[tm][tn], 0, 0, 0);
  }
#undef LOAD_TILE

  if (MODE == MODE_VAL) {
    // ---- direct ushort4 stores to (B,HN,NV,DH); 4 consecutive dh per thread ----
    unsigned short* outs = (unsigned short*)outp;
    const size_t b = (size_t)(bm >> 14);
    const int n0 = bm & (NVc - 1);
#pragma unroll
    for (int tn = 0; tn < 4; ++tn) {
      const int ch0 = bn + wc * 64 + tn * 16 + quad * 4;  // global channel
      const float4 b4 = *(const float4*)&bias[ch0];
      const int h = ch0 >> 5, dh0 = ch0 & 31;
#pragma unroll
      for (int tm = 0; tm < 4; ++tm) {
        const int n = n0 + wr * 64 + tm * 16 + lane15;
        ushort4 o;
        o.x = f2bf(acc[tm][tn][0] + b4.x);
        o.y = f2bf(acc[tm][tn][1] + b4.y);
        o.z = f2bf(acc[tm][tn][2] + b4.z);
        o.w = f2bf(acc[tm][tn][3] + b4.w);
        *(ushort4*)(outs + ((b * HN + h) * NVc + n) * DH + dh0) = o;
      }
    }
  } else if (MODE == MODE_PLAIN) {
    // ---- float4 LDS writes (stride 100, conflict-free), then fused softmax/loc prep ----
    float* Cf = (float*)smem;  // 128 x 100
    __syncthreads();
#pragma unroll
    for (int tn = 0; tn < 4; ++tn) {
      const int col0 = wc * 64 + tn * 16 + quad * 4;
      if (col0 < 96) {
        const float4 b4 = *(const float4*)&bias[col0];
#pragma unroll
        for (int tm = 0; tm < 4; ++tm) {
          const int m = wr * 64 + tm * 16 + lane15;
          float4 v;
          v.x = acc[tm][tn][0] + b4.x;
          v.y = acc[tm][tn][1] + b4.y;
          v.z = acc[tm][tn][2] + b4.z;
          v.w = acc[tm][tn][3] + b4.w;
          *(float4*)&Cf[m * 100 + col0] = v;
        }
      }
    }
    __syncthreads();
#pragma unroll
    for (int i = 0; i < 4; ++i) {
      const int task = i * 256 + t;
      const int h = task & 7, rowl = task >> 3;
      const int bq = bm + rowl;
      const float* row = Cf + rowl * 100;
      const float rx = ref2d[(size_t)bq * 2 + 0];
      const float ry = ref2d[(size_t)bq * 2 + 1];
      const float l0 = row[64 + h * 4 + 0], l1 = row[64 + h * 4 + 1];
      const float l2 = row[64 + h * 4 + 2], l3 = row[64 + h * 4 + 3];
      const float mx = fmaxf(fmaxf(l0, l1), fmaxf(l2, l3));
      float e0 = __expf(l0 - mx), e1 = __expf(l1 - mx), e2 = __expf(l2 - mx), e3 = __expf(l3 - mx);
      const float inv = 1.0f / (e0 + e1 + e2 + e3);
      float ee[4] = {e0, e1, e2, e3};
      unsigned int* m = meta + ((size_t)bq * 8 + h) * 20;
      uint4 pk;
      float4 wts[4];
#pragma unroll
      for (int p = 0; p < PP; ++p) {
        const float a = ee[p] * inv;
        const float ox = row[h * 8 + p * 2 + 0];
        const float oy = row[h * 8 + p * 2 + 1];
        const float x = (rx + ox * (1.0f / HWc)) * (float)HWc - 0.5f;
        const float y = (ry + oy * (1.0f / HWc)) * (float)HWc - 0.5f;
        const float x0f = floorf(x), y0f = floorf(y);
        const int x0 = (int)x0f, y0 = (int)y0f;
        const float wx1 = x - x0f, wx0 = 1.f - wx1;
        const float wy1 = y - y0f, wy0 = 1.f - wy1;
        const bool vx0 = (unsigned)x0 < (unsigned)HWc, vx1 = (unsigned)(x0 + 1) < (unsigned)HWc;
        const bool vy0 = (unsigned)y0 < (unsigned)HWc, vy1 = (unsigned)(y0 + 1) < (unsigned)HWc;
        const int xi0 = min(max(x0, 0), HWc - 1), xi1 = min(max(x0 + 1, 0), HWc - 1);
        const int yi0 = min(max(y0, 0), HWc - 1), yi1 = min(max(y0 + 1, 0), HWc - 1);
        const unsigned pv = (unsigned)xi0 | ((unsigned)yi0 << 8) | ((unsigned)xi1 << 16) | ((unsigned)yi1 << 24);
        if (p == 0) pk.x = pv; else if (p == 1) pk.y = pv; else if (p == 2) pk.z = pv; else pk.w = pv;
        float4 w;
        w.x = (vx0 && vy0) ? a * wx0 * wy0 : 0.f;
        w.y = (vx1 && vy0) ? a * wx1 * wy0 : 0.f;
        w.z = (vx0 && vy1) ? a * wx0 * wy1 : 0.f;
        w.w = (vx1 && vy1) ? a * wx1 * wy1 : 0.f;
        wts[p] = w;
      }
      *(uint4*)m = pk;
#pragma unroll
      for (int p = 0; p < PP; ++p) *(float4*)&m[4 + p * 4] = wts[p];
    }
  } else {
    // ---- MODE_OUT: 2-pass LDS transpose (float4 writes), coalesced resid/store ----
    float* Cf = (float*)smem;  // 64 x 132
    float* outf = (float*)outp;
#pragma unroll
    for (int pass = 0; pass < 2; ++pass) {
      __syncthreads();
      if (wr == pass) {
#pragma unroll
        for (int tn = 0; tn < 4; ++tn) {
          const int col0 = wc * 64 + tn * 16 + quad * 4;   // channel within tile
          const float4 b4 = *(const float4*)&bias[bn + col0];
#pragma unroll
          for (int tm = 0; tm < 4; ++tm) {
            const int rowl = tm * 16 + lane15;             // spatial within half-tile
            float4 v;
            v.x = acc[tm][tn][0] + b4.x;
            v.y = acc[tm][tn][1] + b4.y;
            v.z = acc[tm][tn][2] + b4.z;
            v.w = acc[tm][tn][3] + b4.w;
            *(float4*)&Cf[rowl * 132 + col0] = v;
          }
        }
      }
      __syncthreads();
#pragma unroll
      for (int i = 0; i < 8; ++i) {
        const int id = i * 256 + t;
        const int n = id >> 5, c = id & 31;
        const size_t row = (size_t)bm + pass * 64 + n;
        float4 v = *(const float4*)&Cf[n * 132 + c * 4];
        float4 rs = *(const float4*)(resid + row * 256 + bn + c * 4);
        v.x += rs.x; v.y += rs.y; v.z += rs.z; v.w += rs.w;
        *(float4*)(outf + row * 256 + bn + c * 4) = v;
      }
    }
  }
}

// ---------- gather (bf16 vbuf) + weighted accumulate; bf16 output ----------
// v9: XCD-aware plane swizzle. 256 blocks sharing one (b,h) vbuf plane (1MB)
// + meta slice (0.7MB) are mapped to the SAME XCD (dispatch round-robins
// XCDs by block index => j = xcd + 8*slot). Bijection:
//   j = x + 8*(gi*256 + m),  plane g = x + 8*gi,  member m.
__global__ __launch_bounds__(256) void sample_kernel(
    const unsigned short* __restrict__ vbuf,  // (B,HN,NV,DH) bf16
    const unsigned int* __restrict__ meta,
    unsigned short* __restrict__ outs) {      // (B*NQ, 256) bf16
  const int t = threadIdx.x;
  const int d4 = (t & 7) << 2;   // channel group base: 0,4,...,28
  const int ql = t >> 3;         // 32 queries per block
  const int j = blockIdx.x;
  const int x = j & 7;           // XCD (round-robin by dispatch index)
  const int s = j >> 3;
  const int m_ = s & 255;        // member within plane
  const int gi = s >> 8;         // plane-group on this XCD
  const int sl = x + 8 * gi;     // b*8+h  (all 256 members -> same XCD)
  const int qc = m_;
  const int b = sl >> 3;
  const int h = sl & 7;
  const int q = qc * 32 + ql;
  const size_t bq = (size_t)b * NQc + q;
  const unsigned int* m = meta + ((size_t)bq * 8 + h) * 20;
  const uint4 pk = *(const uint4*)m;
  const unsigned short* vb = vbuf + (size_t)sl * (NVc * DH) + d4;

  float4 acc = {0.f, 0.f, 0.f, 0.f};
#pragma unroll
  for (int p = 0; p < PP; ++p) {
    const unsigned P = (p == 0) ? pk.x : (p == 1) ? pk.y : (p == 2) ? pk.z : pk.w;
    const float4 w = *(const float4*)(m + 4 + p * 4);
    const int x0 = P & 255, y0 = (P >> 8) & 255, x1 = (P >> 16) & 255, y1 = P >> 24;
    const int r0 = y0 << 12, r1 = y1 << 12;
    const ushort4 v00 = *(const ushort4*)(vb + r0 + (x0 << 5));
    const ushort4 v10 = *(const ushort4*)(vb + r0 + (x1 << 5));
    const ushort4 v01 = *(const ushort4*)(vb + r1 + (x0 << 5));
    const ushort4 v11 = *(const ushort4*)(vb + r1 + (x1 << 5));
    acc.x += w.x * bf2f(v00.x); acc.y += w.x * bf2f(v00.y);
    acc.z += w.x * bf2f(v00.z); acc.w += w.x * bf2f(v00.w);
    acc.x += w.y * bf2f(v10.x); acc.y += w.y * bf2f(v10.y);
    acc.z += w.y * bf2f(v10.z); acc.w += w.y * bf2f(v10.w);
    acc.x += w.z * bf2f(v01.x); acc.y += w.z * bf2f(v01.y);
    acc.z += w.z * bf2f(v01.z); acc.w += w.z * bf2f(v01.w);
    acc.x += w.w * bf2f(v11.x); acc.y += w.w * bf2f(v11.y);
    acc.z += w.w * bf2f(v11.z); acc.w += w.w * bf2f(v11.w);
  }
  ushort4 o;
  o.x = f2bf(acc.x); o.y = f2bf(acc.y); o.z = f2bf(acc.z); o.w = f2bf(acc.w);
  *(ushort4*)(outs + bq * EE + h * DH + d4) = o;
}

extern "C" void kernel_launch(void* const* d_in, const int* in_sizes, int n_in,
                              void* d_out, int out_size, void* d_ws, size_t ws_size,
                              hipStream_t stream) {
  const float* query = (const float*)d_in[0];
  const float* value = (const float*)d_in[1];
  const float* ref2d = (const float*)d_in[2];
  const float* Woff  = (const float*)d_in[4];
  const float* boff  = (const float*)d_in[5];
  const float* Wattn = (const float*)d_in[6];
  const float* battn = (const float*)d_in[7];
  const float* Wval  = (const float*)d_in[8];
  const float* bval  = (const float*)d_in[9];
  const float* Wout  = (const float*)d_in[10];
  const float* bout  = (const float*)d_in[11];
  float* out = (float*)d_out;

  unsigned short* vbuf = (unsigned short*)d_ws;                 // 33,554,432 us (64 MB)
  unsigned int* meta   = (unsigned int*)(vbuf + 33554432);      // 10,485,760 u (40 MB)
  unsigned short* sbuf = (unsigned short*)(meta + 10485760);    // 16,777,216 us (32 MB)
  unsigned short* wvt  = sbuf + 16777216;                       // 65536
  unsigned short* wot  = wvt + 65536;                           // 65536
  unsigned short* wct  = wot + 65536;                           // 32768
  float* bcat          = (float*)(wct + 32768);                 // 128

  wprep<<<641, 256, 0, stream>>>(Wval, Wout, Woff, Wattn, boff, battn, wvt, wot, wct, bcat);

  mfma_gemm<MODE_VAL, false><<<dim3(1024, 2), 256, 0, stream>>>(
      (const void*)value, wvt, bval, nullptr, nullptr, nullptr, (void*)vbuf);

  mfma_gemm<MODE_PLAIN, false><<<dim3(512, 1), 256, 0, stream>>>(
      (const void*)query, wct, bcat, nullptr, ref2d, meta, nullptr);

  sample_kernel<<<16384, 256, 0, stream>>>(vbuf, meta, sbuf);

  mfma_gemm<MODE_OUT, true><<<dim3(512, 2), 256, 0, stream>>>(
      (const void*)sbuf, wot, bout, query, nullptr, nullptr, (void*)out);
}

// Round 10
// 416.509 us; speedup vs baseline: 1.1678x; 1.0046x over previous
//
#include <hip/hip_runtime.h>

typedef short s16x8 __attribute__((ext_vector_type(8)));
typedef float f32x4 __attribute__((ext_vector_type(4)));

#define HN 8
#define PP 4
#define DH 32
#define NQc 8192
#define NVc 16384
#define EE 256
#define HWc 128

__device__ __forceinline__ unsigned short f2bf(float x) {
  unsigned u = __float_as_uint(x);
  u += 0x7FFF + ((u >> 16) & 1);  // RNE
  return (unsigned short)(u >> 16);
}
__device__ __forceinline__ float bf2f(unsigned short h) {
  return __uint_as_float(((unsigned)h) << 16);
}

// ---------- weight prep: transpose+convert to bf16 [N][K], build bcat ----------
__global__ __launch_bounds__(256) void wprep(
    const float* __restrict__ Wval, const float* __restrict__ Wout,
    const float* __restrict__ Woff, const float* __restrict__ Wattn,
    const float* __restrict__ boff, const float* __restrict__ battn,
    unsigned short* __restrict__ wvt, unsigned short* __restrict__ wot,
    unsigned short* __restrict__ wct, float* __restrict__ bcat) {
  int g = blockIdx.x * 256 + threadIdx.x;
  if (g < 65536) {
    int n = g >> 8, k = g & 255;
    wvt[n * 256 + k] = f2bf(Wval[k * 256 + n]);
  } else if (g < 131072) {
    int g2 = g - 65536;
    int n = g2 >> 8, k = g2 & 255;
    wot[n * 256 + k] = f2bf(Wout[k * 256 + n]);
  } else if (g < 163840) {
    int g2 = g - 131072;
    int n = g2 >> 8, k = g2 & 255;
    float v = 0.f;
    if (n < 64) v = Woff[k * 64 + n];
    else if (n < 96) v = Wattn[k * 32 + (n - 64)];
    wct[n * 256 + k] = f2bf(v);
  } else if (g < 163968) {
    int c = g - 163840;
    bcat[c] = (c < 64) ? boff[c] : ((c < 96) ? battn[c - 64] : 0.f);
  }
}

// ---------- bf16 MFMA GEMM, BM=BN=128, BK=32, 4 waves x (4x4) 16x16x32 tiles ----
// v10 = v9 + prefetch DEPTH 2 via doubled register staging sets (A/B).
// Barrier structure, LDS single-buffer, staging map, MFMA order, epilogues:
// byte-identical to v9 (verified, VAL=83us). Only the register dataflow is
// deeper: tile k+2's global loads issue where k+1's used to, so consumption
// trails issue by ~2 iterations (~1600cyc) > ~900cyc HBM latency -> the
// ~500cyc/K-step load stall (the 2.45 TB/s plateau) disappears. No race
// surface: within-thread reg deps only (compiler vmcnt), unlike r6/r7.
#define MODE_VAL 0    // epilogue: bf16 direct store -> (B,HN,NV,DH)
#define MODE_PLAIN 1  // epilogue: fused softmax/loc prep -> meta
#define MODE_OUT 2    // epilogue: 2-pass LDS transpose, +bias+resid, f32 store

template <int MODE>
struct SmemBytes { static constexpr int v = 20480; };           // staging only
template <> struct SmemBytes<MODE_PLAIN> { static constexpr int v = 51200; };  // 128x100 f32
template <> struct SmemBytes<MODE_OUT>   { static constexpr int v = 33792; };  // 64x132 f32

template <int MODE, bool ABF16>
__global__ __launch_bounds__(256) void mfma_gemm(
    const void* __restrict__ Ain, const unsigned short* __restrict__ Wt,
    const float* __restrict__ bias, const float* __restrict__ resid,
    const float* __restrict__ ref2d, unsigned int* __restrict__ meta,
    void* __restrict__ outp) {
  __shared__ __align__(16) char smem[SmemBytes<MODE>::v];
  unsigned short* As = (unsigned short*)smem;            // 128 x 40 shorts
  unsigned short* Ws = As + 128 * 40;                    // 128 x 40 shorts
  const int t = threadIdx.x;
  const int lane = t & 63, wave = t >> 6;
  const int lane15 = lane & 15, quad = lane >> 4;
  const int wr = wave >> 1, wc = wave & 1;
  const int bm = blockIdx.x * 128, bn = blockIdx.y * 128;

  f32x4 acc[4][4];
#pragma unroll
  for (int i = 0; i < 4; ++i)
#pragma unroll
    for (int j = 0; j < 4; ++j)
#pragma unroll
      for (int r = 0; r < 4; ++r) acc[i][j][r] = 0.f;

  const int ar = t >> 3, ac = (t & 7) * 4;   // f32 A staging
  const int wr2 = t >> 1, wcp = (t & 1) * 2; // bf16 chunk-pair staging

  // two named register staging sets (rule #20: no runtime-indexed reg arrays)
  float4 avA[4], avB[4];
  uint4 abA0, abA1, abB0, abB1, wvA0, wvA1, wvB0, wvB1;

#define LOAD_TILE(K0, S)                                                       \
  do {                                                                         \
    if (!ABF16) {                                                              \
      const float* Af = (const float*)Ain;                                     \
      _Pragma("unroll") for (int i = 0; i < 4; ++i)                            \
          av##S[i] = *(const float4*)(Af + (size_t)(bm + ar + i * 32) * 256 +  \
                                      (K0) + ac);                              \
    } else {                                                                   \
      const unsigned short* Ab = (const unsigned short*)Ain;                   \
      ab##S##0 = *(const uint4*)(Ab + (size_t)(bm + wr2) * 256 + (K0) + wcp * 8); \
      ab##S##1 = *(const uint4*)(Ab + (size_t)(bm + wr2) * 256 + (K0) + wcp * 8 + 8); \
    }                                                                          \
    wv##S##0 = *(const uint4*)(Wt + (size_t)(bn + wr2) * 256 + (K0) + wcp * 8);   \
    wv##S##1 = *(const uint4*)(Wt + (size_t)(bn + wr2) * 256 + (K0) + wcp * 8 + 8); \
  } while (0)

#define STAGE_TILE(S)                                                          \
  do {                                                                         \
    if (!ABF16) {                                                              \
      _Pragma("unroll") for (int i = 0; i < 4; ++i) {                          \
        ushort4 c;                                                             \
        c.x = f2bf(av##S[i].x); c.y = f2bf(av##S[i].y);                        \
        c.z = f2bf(av##S[i].z); c.w = f2bf(av##S[i].w);                        \
        *(ushort4*)&As[(ar + i * 32) * 40 + ac] = c;                           \
      }                                                                        \
    } else {                                                                   \
      *(uint4*)&As[wr2 * 40 + wcp * 8] = ab##S##0;                             \
      *(uint4*)&As[wr2 * 40 + wcp * 8 + 8] = ab##S##1;                         \
    }                                                                          \
    *(uint4*)&Ws[wr2 * 40 + wcp * 8] = wv##S##0;                               \
    *(uint4*)&Ws[wr2 * 40 + wcp * 8 + 8] = wv##S##1;                           \
  } while (0)

#define COMPUTE()                                                              \
  do {                                                                         \
    s16x8 af[4], bfr[4];                                                       \
    _Pragma("unroll") for (int tm = 0; tm < 4; ++tm)                           \
        af[tm] = *(const s16x8*)&As[(wr * 64 + tm * 16 + lane15) * 40 + quad * 8]; \
    _Pragma("unroll") for (int tn = 0; tn < 4; ++tn)                           \
        bfr[tn] = *(const s16x8*)&Ws[(wc * 64 + tn * 16 + lane15) * 40 + quad * 8]; \
    _Pragma("unroll") for (int tm = 0; tm < 4; ++tm)                           \
        _Pragma("unroll") for (int tn = 0; tn < 4; ++tn)                       \
            acc[tm][tn] = __builtin_amdgcn_mfma_f32_16x16x32_bf16(             \
                bfr[tn], af[tm], acc[tm][tn], 0, 0, 0);                        \
  } while (0)

  LOAD_TILE(0, A);   // tiles 0,64,128,192 go through set A
  LOAD_TILE(32, B);  // tiles 32,96,160,224 go through set B

  for (int k0 = 0; k0 < 256; k0 += 64) {
    // ---- K-step using set A (tile k0) ----
    __syncthreads();          // previous tile's readers done
    STAGE_TILE(A);
    __syncthreads();
    if (k0 < 192) LOAD_TILE(k0 + 64, A);  // depth-2 prefetch
    COMPUTE();
    // ---- K-step using set B (tile k0+32) ----
    __syncthreads();
    STAGE_TILE(B);
    __syncthreads();
    if (k0 < 160) LOAD_TILE(k0 + 96, B);  // depth-2 prefetch
    COMPUTE();
  }
#undef LOAD_TILE
#undef STAGE_TILE
#undef COMPUTE

  if (MODE == MODE_VAL) {
    // ---- direct ushort4 stores to (B,HN,NV,DH); 4 consecutive dh per thread ----
    unsigned short* outs = (unsigned short*)outp;
    const size_t b = (size_t)(bm >> 14);
    const int n0 = bm & (NVc - 1);
#pragma unroll
    for (int tn = 0; tn < 4; ++tn) {
      const int ch0 = bn + wc * 64 + tn * 16 + quad * 4;  // global channel
      const float4 b4 = *(const float4*)&bias[ch0];
      const int h = ch0 >> 5, dh0 = ch0 & 31;
#pragma unroll
      for (int tm = 0; tm < 4; ++tm) {
        const int n = n0 + wr * 64 + tm * 16 + lane15;
        ushort4 o;
        o.x = f2bf(acc[tm][tn][0] + b4.x);
        o.y = f2bf(acc[tm][tn][1] + b4.y);
        o.z = f2bf(acc[tm][tn][2] + b4.z);
        o.w = f2bf(acc[tm][tn][3] + b4.w);
        *(ushort4*)(outs + ((b * HN + h) * NVc + n) * DH + dh0) = o;
      }
    }
  } else if (MODE == MODE_PLAIN) {
    // ---- float4 LDS writes (stride 100, conflict-free), then fused softmax/loc prep ----
    float* Cf = (float*)smem;  // 128 x 100
    __syncthreads();
#pragma unroll
    for (int tn = 0; tn < 4; ++tn) {
      const int col0 = wc * 64 + tn * 16 + quad * 4;
      if (col0 < 96) {
        const float4 b4 = *(const float4*)&bias[col0];
#pragma unroll
        for (int tm = 0; tm < 4; ++tm) {
          const int m = wr * 64 + tm * 16 + lane15;
          float4 v;
          v.x = acc[tm][tn][0] + b4.x;
          v.y = acc[tm][tn][1] + b4.y;
          v.z = acc[tm][tn][2] + b4.z;
          v.w = acc[tm][tn][3] + b4.w;
          *(float4*)&Cf[m * 100 + col0] = v;
        }
      }
    }
    __syncthreads();
#pragma unroll
    for (int i = 0; i < 4; ++i) {
      const int task = i * 256 + t;
      const int h = task & 7, rowl = task >> 3;
      const int bq = bm + rowl;
      const float* row = Cf + rowl * 100;
      const float rx = ref2d[(size_t)bq * 2 + 0];
      const float ry = ref2d[(size_t)bq * 2 + 1];
      const float l0 = row[64 + h * 4 + 0], l1 = row[64 + h * 4 + 1];
      const float l2 = row[64 + h * 4 + 2], l3 = row[64 + h * 4 + 3];
      const float mx = fmaxf(fmaxf(l0, l1), fmaxf(l2, l3));
      float e0 = __expf(l0 - mx), e1 = __expf(l1 - mx), e2 = __expf(l2 - mx), e3 = __expf(l3 - mx);
      const float inv = 1.0f / (e0 + e1 + e2 + e3);
      float ee[4] = {e0, e1, e2, e3};
      unsigned int* m = meta + ((size_t)bq * 8 + h) * 20;
      uint4 pk;
      float4 wts[4];
#pragma unroll
      for (int p = 0; p < PP; ++p) {
        const float a = ee[p] * inv;
        const float ox = row[h * 8 + p * 2 + 0];
        const float oy = row[h * 8 + p * 2 + 1];
        const float x = (rx + ox * (1.0f / HWc)) * (float)HWc - 0.5f;
        const float y = (ry + oy * (1.0f / HWc)) * (float)HWc - 0.5f;
        const float x0f = floorf(x), y0f = floorf(y);
        const int x0 = (int)x0f, y0 = (int)y0f;
        const float wx1 = x - x0f, wx0 = 1.f - wx1;
        const float wy1 = y - y0f, wy0 = 1.f - wy1;
        const bool vx0 = (unsigned)x0 < (unsigned)HWc, vx1 = (unsigned)(x0 + 1) < (unsigned)HWc;
        const bool vy0 = (unsigned)y0 < (unsigned)HWc, vy1 = (unsigned)(y0 + 1) < (unsigned)HWc;
        const int xi0 = min(max(x0, 0), HWc - 1), xi1 = min(max(x0 + 1, 0), HWc - 1);
        const int yi0 = min(max(y0, 0), HWc - 1), yi1 = min(max(y0 + 1, 0), HWc - 1);
        const unsigned pv = (unsigned)xi0 | ((unsigned)yi0 << 8) | ((unsigned)xi1 << 16) | ((unsigned)yi1 << 24);
        if (p == 0) pk.x = pv; else if (p == 1) pk.y = pv; else if (p == 2) pk.z = pv; else pk.w = pv;
        float4 w;
        w.x = (vx0 && vy0) ? a * wx0 * wy0 : 0.f;
        w.y = (vx1 && vy0) ? a * wx1 * wy0 : 0.f;
        w.z = (vx0 && vy1) ? a * wx0 * wy1 : 0.f;
        w.w = (vx1 && vy1) ? a * wx1 * wy1 : 0.f;
        wts[p] = w;
      }
      *(uint4*)m = pk;
#pragma unroll
      for (int p = 0; p < PP; ++p) *(float4*)&m[4 + p * 4] = wts[p];
    }
  } else {
    // ---- MODE_OUT: 2-pass LDS transpose (float4 writes), coalesced resid/store ----
    float* Cf = (float*)smem;  // 64 x 132
    float* outf = (float*)outp;
#pragma unroll
    for (int pass = 0; pass < 2; ++pass) {
      __syncthreads();
      if (wr == pass) {
#pragma unroll
        for (int tn = 0; tn < 4; ++tn) {
          const int col0 = wc * 64 + tn * 16 + quad * 4;   // channel within tile
          const float4 b4 = *(const float4*)&bias[bn + col0];
#pragma unroll
          for (int tm = 0; tm < 4; ++tm) {
            const int rowl = tm * 16 + lane15;             // spatial within half-tile
            float4 v;
            v.x = acc[tm][tn][0] + b4.x;
            v.y = acc[tm][tn][1] + b4.y;
            v.z = acc[tm][tn][2] + b4.z;
            v.w = acc[tm][tn][3] + b4.w;
            *(float4*)&Cf[rowl * 132 + col0] = v;
          }
        }
      }
      __syncthreads();
#pragma unroll
      for (int i = 0; i < 8; ++i) {
        const int id = i * 256 + t;
        const int n = id >> 5, c = id & 31;
        const size_t row = (size_t)bm + pass * 64 + n;
        float4 v = *(const float4*)&Cf[n * 132 + c * 4];
        float4 rs = *(const float4*)(resid + row * 256 + bn + c * 4);
        v.x += rs.x; v.y += rs.y; v.z += rs.z; v.w += rs.w;
        *(float4*)(outf + row * 256 + bn + c * 4) = v;
      }
    }
  }
}

// ---------- gather (bf16 vbuf) + weighted accumulate; bf16 output ----------
// XCD-aware plane swizzle (v9, verified): 256 blocks sharing one (b,h) vbuf
// plane (1MB) + meta slice map to the SAME XCD. j = x + 8*(gi*256 + m).
__global__ __launch_bounds__(256) void sample_kernel(
    const unsigned short* __restrict__ vbuf,  // (B,HN,NV,DH) bf16
    const unsigned int* __restrict__ meta,
    unsigned short* __restrict__ outs) {      // (B*NQ, 256) bf16
  const int t = threadIdx.x;
  const int d4 = (t & 7) << 2;   // channel group base: 0,4,...,28
  const int ql = t >> 3;         // 32 queries per block
  const int j = blockIdx.x;
  const int x = j & 7;           // XCD (round-robin by dispatch index)
  const int s = j >> 3;
  const int m_ = s & 255;        // member within plane
  const int gi = s >> 8;         // plane-group on this XCD
  const int sl = x + 8 * gi;     // b*8+h  (all 256 members -> same XCD)
  const int qc = m_;
  const int b = sl >> 3;
  const int h = sl & 7;
  const int q = qc * 32 + ql;
  const size_t bq = (size_t)b * NQc + q;
  const unsigned int* m = meta + ((size_t)bq * 8 + h) * 20;
  const uint4 pk = *(const uint4*)m;
  const unsigned short* vb = vbuf + (size_t)sl * (NVc * DH) + d4;

  float4 acc = {0.f, 0.f, 0.f, 0.f};
#pragma unroll
  for (int p = 0; p < PP; ++p) {
    const unsigned P = (p == 0) ? pk.x : (p == 1) ? pk.y : (p == 2) ? pk.z : pk.w;
    const float4 w = *(const float4*)(m + 4 + p * 4);
    const int x0 = P & 255, y0 = (P >> 8) & 255, x1 = (P >> 16) & 255, y1 = P >> 24;
    const int r0 = y0 << 12, r1 = y1 << 12;
    const ushort4 v00 = *(const ushort4*)(vb + r0 + (x0 << 5));
    const ushort4 v10 = *(const ushort4*)(vb + r0 + (x1 << 5));
    const ushort4 v01 = *(const ushort4*)(vb + r1 + (x0 << 5));
    const ushort4 v11 = *(const ushort4*)(vb + r1 + (x1 << 5));
    acc.x += w.x * bf2f(v00.x); acc.y += w.x * bf2f(v00.y);
    acc.z += w.x * bf2f(v00.z); acc.w += w.x * bf2f(v00.w);
    acc.x += w.y * bf2f(v10.x); acc.y += w.y * bf2f(v10.y);
    acc.z += w.y * bf2f(v10.z); acc.w += w.y * bf2f(v10.w);
    acc.x += w.z * bf2f(v01.x); acc.y += w.z * bf2f(v01.y);
    acc.z += w.z * bf2f(v01.z); acc.w += w.z * bf2f(v01.w);
    acc.x += w.w * bf2f(v11.x); acc.y += w.w * bf2f(v11.y);
    acc.z += w.w * bf2f(v11.z); acc.w += w.w * bf2f(v11.w);
  }
  ushort4 o;
  o.x = f2bf(acc.x); o.y = f2bf(acc.y); o.z = f2bf(acc.z); o.w = f2bf(acc.w);
  *(ushort4*)(outs + bq * EE + h * DH + d4) = o;
}

extern "C" void kernel_launch(void* const* d_in, const int* in_sizes, int n_in,
                              void* d_out, int out_size, void* d_ws, size_t ws_size,
                              hipStream_t stream) {
  const float* query = (const float*)d_in[0];
  const float* value = (const float*)d_in[1];
  const float* ref2d = (const float*)d_in[2];
  const float* Woff  = (const float*)d_in[4];
  const float* boff  = (const float*)d_in[5];
  const float* Wattn = (const float*)d_in[6];
  const float* battn = (const float*)d_in[7];
  const float* Wval  = (const float*)d_in[8];
  const float* bval  = (const float*)d_in[9];
  const float* Wout  = (const float*)d_in[10];
  const float* bout  = (const float*)d_in[11];
  float* out = (float*)d_out;

  unsigned short* vbuf = (unsigned short*)d_ws;                 // 33,554,432 us (64 MB)
  unsigned int* meta   = (unsigned int*)(vbuf + 33554432);      // 10,485,760 u (40 MB)
  unsigned short* sbuf = (unsigned short*)(meta + 10485760);    // 16,777,216 us (32 MB)
  unsigned short* wvt  = sbuf + 16777216;                       // 65536
  unsigned short* wot  = wvt + 65536;                           // 65536
  unsigned short* wct  = wot + 65536;                           // 32768
  float* bcat          = (float*)(wct + 32768);                 // 128

  wprep<<<641, 256, 0, stream>>>(Wval, Wout, Woff, Wattn, boff, battn, wvt, wot, wct, bcat);

  mfma_gemm<MODE_VAL, false><<<dim3(1024, 2), 256, 0, stream>>>(
      (const void*)value, wvt, bval, nullptr, nullptr, nullptr, (void*)vbuf);

  mfma_gemm<MODE_PLAIN, false><<<dim3(512, 1), 256, 0, stream>>>(
      (const void*)query, wct, bcat, nullptr, ref2d, meta, nullptr);

  sample_kernel<<<16384, 256, 0, stream>>>(vbuf, meta, sbuf);

  mfma_gemm<MODE_OUT, true><<<dim3(512, 2), 256, 0, stream>>>(
      (const void*)sbuf, wot, bout, query, nullptr, nullptr, (void*)out);
}